// Round 3
// baseline (2730.097 us; speedup 1.0000x reference)
//
#include <hip/hip_runtime.h>
#include <hip/hip_bf16.h>
#include <math.h>

#define XKTOT 1196
#define XKP   1216

static __device__ __forceinline__ float sigmoidf_(float x){ return 1.f/(1.f+expf(-x)); }

// ---------- generic 32x32 tiled transpose: in[R][C] -> out[C][R] ----------
__global__ __launch_bounds__(256) void k_transpose(const float* __restrict__ in,
                                                   float* __restrict__ out, int R, int C) {
  __shared__ float tile[32][33];
  int c0 = blockIdx.x * 32, r0 = blockIdx.y * 32;
  int tx = threadIdx.x & 31, ty = threadIdx.x >> 5;   // ty 0..7
  for (int i = 0; i < 32; i += 8) {
    int r = r0 + ty + i, c = c0 + tx;
    tile[ty + i][tx] = (r < R && c < C) ? in[(size_t)r * C + c] : 0.f;
  }
  __syncthreads();
  for (int i = 0; i < 32; i += 8) {
    int c = c0 + ty + i, r = r0 + tx;
    if (c < C && r < R) out[(size_t)c * R + r] = tile[tx][ty + i];
  }
}

// ---------- Wcat[j][0:684]=W_ih[j], [684:1196]=W_hh[j], pad zeros ----------
__global__ __launch_bounds__(256) void k_wcat(const float* __restrict__ W_ih,
                                              const float* __restrict__ W_hh,
                                              float* __restrict__ Wcat) {
  int j = blockIdx.x;
  for (int c = threadIdx.x; c < XKP; c += 256) {
    float v;
    if (c < 684)        v = W_ih[(size_t)j * 684 + c];
    else if (c < 1196)  v = W_hh[(size_t)j * 512 + (c - 684)];
    else                v = 0.f;
    Wcat[(size_t)j * XKP + c] = v;
  }
}

// ---------- objectness mask + top-16 order stat + enc mean ----------
__global__ __launch_bounds__(128) void k_mask(const float* __restrict__ objs,
                                              const float* __restrict__ rcl,
                                              const float* __restrict__ avx,
                                              const float* __restrict__ enc,
                                              float* __restrict__ maskf,
                                              float* __restrict__ encmean,
                                              float* __restrict__ out_mask) {
  int b = blockIdx.x, k = threadIdx.x;
  __shared__ float dsh[128];
  __shared__ float maxd;
  float s0 = objs[(size_t)(b * 128 + k) * 2 + 0];
  float s1 = objs[(size_t)(b * 128 + k) * 2 + 1];
  float mx = fmaxf(s0, s1);
  float e0 = expf(s0 - mx), e1 = expf(s1 - mx);
  float p  = e1 / (e0 + e1);
  bool om  = p > 0.75f;
  float dx = rcl[b * 3 + 0] - avx[(size_t)(b * 128 + k) * 3 + 0];
  float dy = rcl[b * 3 + 1] - avx[(size_t)(b * 128 + k) * 3 + 1];
  float dz = rcl[b * 3 + 2] - avx[(size_t)(b * 128 + k) * 3 + 2];
  float dist = sqrtf(dx * dx + dy * dy + dz * dz);
  float dm = om ? dist : INFINITY;
  dsh[k] = dm;
  __syncthreads();
  // 16th order statistic (counting duplicates), inf-aware
  float v = dm; int clt = 0, cle = 0;
  for (int j = 0; j < 128; j++) { float o = dsh[j]; clt += (o < v); cle += (o <= v); }
  if (clt < 16 && cle >= 16) maxd = v;   // all candidates share the same value
  __syncthreads();
  bool msk = om && (dm <= maxd);
  maskf[b * 128 + k]    = msk ? 1.f : 0.f;
  out_mask[b * 128 + k] = msk ? 1.f : 0.f;
  // enc mean over K (thread k plays the v-channel role; coalesced over v)
  float s = 0.f;
  for (int kk = 0; kk < 128; kk++) s += enc[(size_t)(b * 128 + kk) * 128 + k];
  encmean[b * 128 + k] = s * (1.f / 128.f);
}

// ---------- h0/c0 init: [encmean|rof] @ W_init^T + b ----------
__global__ __launch_bounds__(512) void k_init(const float* __restrict__ encm,
                                              const float* __restrict__ rof,
                                              const float* __restrict__ wihT,
                                              const float* __restrict__ wicT,
                                              const float* __restrict__ bh,
                                              const float* __restrict__ bc,
                                              float* __restrict__ h, float* __restrict__ c) {
  int b = blockIdx.x, d = threadIdx.x;
  __shared__ float xin[384];
  if (d < 128) xin[d] = encm[b * 128 + d];
  else if (d < 384) xin[d] = rof[(size_t)b * 256 + (d - 128)];
  __syncthreads();
  float ah = bh[d], ac = bc[d];
  for (int i = 0; i < 384; i++) {
    float x = xin[i];
    ah += x * wihT[(size_t)i * 512 + d];
    ac += x * wicT[(size_t)i * 512 + d];
  }
  h[(size_t)b * 512 + d] = ah;
  c[(size_t)b * 512 + d] = ac;
}

// ---------- att1[b,k,a] = enc[b,k,:] . W_enc_att[a,:] + b_enc ----------
__global__ __launch_bounds__(512) void k_att1(const float* __restrict__ enc,
                                              const float* __restrict__ weT,  // [128][512]
                                              const float* __restrict__ b_enc,
                                              float* __restrict__ att1) {
  int b = blockIdx.x >> 3, k0 = (blockIdx.x & 7) * 16;
  int a = threadIdx.x;
  __shared__ float es[16][128];
  for (int i = threadIdx.x; i < 16 * 128; i += 512)
    es[i >> 7][i & 127] = enc[(size_t)(b * 128 + k0 + (i >> 7)) * 128 + (i & 127)];
  __syncthreads();
  float acc[16];
  float bb = b_enc[a];
#pragma unroll
  for (int kk = 0; kk < 16; kk++) acc[kk] = bb;
  for (int i = 0; i < 128; i++) {
    float w = weT[(size_t)i * 512 + a];
#pragma unroll
    for (int kk = 0; kk < 16; kk++) acc[kk] += w * es[kk][i];
  }
#pragma unroll
  for (int kk = 0; kk < 16; kk++)
    att1[(size_t)(b * 128 + k0 + kk) * 512 + a] = acc[kk];
}

// ---------- per-step fused attention + softmax + awe + gate + X build ----------
__global__ __launch_bounds__(512) void k_step_att(
    const float* __restrict__ att1, const float* __restrict__ h,
    const float* __restrict__ wdT, const float* __restrict__ b_dec,
    const float* __restrict__ wfull, const float* __restrict__ bfull,
    const float* __restrict__ enc, const float* __restrict__ maskf,
    const float* __restrict__ wfbT, const float* __restrict__ b_fbeta,
    const float* __restrict__ rof, const float* __restrict__ embt,
    const float* __restrict__ iemb, const int* __restrict__ lidx,
    const int* __restrict__ llen, float* __restrict__ X,
    float* __restrict__ alphas_out, int t) {
  int b = blockIdx.x, tid = threadIdx.x;
  __shared__ float hs[512], att2[512], wf[512], attk[128], alph[128], awes[128];
  __shared__ float red1[2], red2[2];
  hs[tid] = h[(size_t)b * 512 + tid];
  wf[tid] = wfull[tid];
  __syncthreads();
  // att2[a] = h . W_dec_att[a,:] + b_dec[a]
  {
    float acc = b_dec[tid];
    for (int i = 0; i < 512; i++) acc += hs[i] * wdT[(size_t)i * 512 + tid];
    att2[tid] = acc;
  }
  __syncthreads();
  // att[k] = relu(att1+att2) . w_full + b_full   (4 threads per k)
  int k = tid >> 2, j = tid & 3;
  {
    const float4* a1 = (const float4*)(att1 + (size_t)(b * 128 + k) * 512 + j * 128);
    float s = 0.f;
#pragma unroll 4
    for (int i = 0; i < 32; i++) {
      float4 v = a1[i];
      int base = j * 128 + i * 4;
      s += fmaxf(v.x + att2[base + 0], 0.f) * wf[base + 0];
      s += fmaxf(v.y + att2[base + 1], 0.f) * wf[base + 1];
      s += fmaxf(v.z + att2[base + 2], 0.f) * wf[base + 2];
      s += fmaxf(v.w + att2[base + 3], 0.f) * wf[base + 3];
    }
    s += __shfl_xor(s, 1);
    s += __shfl_xor(s, 2);
    if (j == 0) attk[k] = s + bfull[0];
  }
  __syncthreads();
  // masked softmax over K=128 (threads 0..127)
  float mk = 0.f, av = 0.f;
  if (tid < 128) { mk = maskf[b * 128 + tid]; av = attk[tid]; }
  float nv = (tid < 128 && mk != 0.f) ? av : -INFINITY;
  float wm = nv;
#pragma unroll
  for (int o = 32; o > 0; o >>= 1) wm = fmaxf(wm, __shfl_xor(wm, o));
  if (tid < 128 && (tid & 63) == 0) red1[tid >> 6] = wm;
  __syncthreads();
  float m = fmaxf(red1[0], red1[1]);
  float e = 0.f;
  if (tid < 128 && mk != 0.f) e = expf(av - m);
  float sred = e;
#pragma unroll
  for (int o = 32; o > 0; o >>= 1) sred += __shfl_xor(sred, o);
  if (tid < 128 && (tid & 63) == 0) red2[tid >> 6] = sred;
  __syncthreads();
  float dsum = red2[0] + red2[1];
  float alpha = (dsum > 0.f) ? e / fmaxf(dsum, 1e-30f) : 0.f;
  int active = t < llen[b];
  if (tid < 128) {
    alph[tid] = alpha;
    alphas_out[(size_t)(b * 32 + t) * 128 + tid] = active ? alpha : 0.f;
  }
  __syncthreads();
  // awe[v] = sum_k alpha[k]*enc[b,k,v]  (threads 0..127 own v)
  float awe_v = 0.f;
  if (tid < 128) {
    for (int kk = 0; kk < 128; kk++)
      awe_v += alph[kk] * enc[(size_t)(b * 128 + kk) * 128 + tid];
  }
  // gate[v] = sigmoid(h . W_fbeta[v,:] + b)  (4 threads per v)
  {
    int v = tid >> 2;
    float g = 0.f;
    for (int ii = 0; ii < 128; ii++) {
      int i = j * 128 + ii;
      g += hs[i] * wfbT[(size_t)i * 128 + v];
    }
    g += __shfl_xor(g, 1);
    g += __shfl_xor(g, 2);
    if (j == 0) attk[v] = sigmoidf_(g + b_fbeta[v]);   // reuse attk as gate store
  }
  __syncthreads();
  if (tid < 128) awes[tid] = awe_v * attk[tid];
  __syncthreads();
  // build X row b: [emb(300) | awe(128) | rof(256) | h(512) | pad(20)]
  const float* esrc = (t == 0) ? iemb : (embt + (size_t)lidx[b * 32 + (t - 1)] * 300);
  for (int c = tid; c < XKP; c += 512) {
    float val;
    if (c < 300)       val = esrc[c];
    else if (c < 428)  val = awes[c - 300];
    else if (c < 684)  val = rof[(size_t)b * 256 + (c - 428)];
    else if (c < 1196) val = hs[c - 684];
    else               val = 0.f;
    X[(size_t)b * XKP + c] = val;
  }
}

// ---------- tiled fp32 GEMM: C[z][128,N] = A[128,K] * B[N,K]^T (split-K via z) ----------
__global__ __launch_bounds__(256) void k_gemm(const float* __restrict__ Am, int lda,
                                              const float* __restrict__ Bw, int ldb, int N,
                                              int klen, float* __restrict__ Cpart, int ldc) {
  int n0 = blockIdx.x * 64;
  int m0 = blockIdx.y * 64;
  int kstart = blockIdx.z * klen;
  float* Cout = Cpart + (size_t)blockIdx.z * 128 * ldc;
  int tc = threadIdx.x & 15, tr = threadIdx.x >> 4;
  __shared__ float As[16][68];
  __shared__ float Bs[16][68];
  float acc[4][4];
#pragma unroll
  for (int r = 0; r < 4; r++)
#pragma unroll
    for (int cc = 0; cc < 4; cc++) acc[r][cc] = 0.f;
  int srow = threadIdx.x >> 2, sq = threadIdx.x & 3;
  bool bok = (n0 + srow) < N;
  const float* aSrc = Am + (size_t)(m0 + srow) * lda + sq * 4;
  const float* bSrc = Bw + (size_t)(n0 + srow) * ldb + sq * 4;
  for (int k0 = kstart; k0 < kstart + klen; k0 += 16) {
    float4 va = *(const float4*)(aSrc + k0);
    float4 vb;
    if (bok) vb = *(const float4*)(bSrc + k0);
    else { vb.x = vb.y = vb.z = vb.w = 0.f; }
    As[sq * 4 + 0][srow] = va.x; As[sq * 4 + 1][srow] = va.y;
    As[sq * 4 + 2][srow] = va.z; As[sq * 4 + 3][srow] = va.w;
    Bs[sq * 4 + 0][srow] = vb.x; Bs[sq * 4 + 1][srow] = vb.y;
    Bs[sq * 4 + 2][srow] = vb.z; Bs[sq * 4 + 3][srow] = vb.w;
    __syncthreads();
#pragma unroll
    for (int ki = 0; ki < 16; ki++) {
      float4 a  = *(const float4*)&As[ki][tr * 4];
      float4 bv = *(const float4*)&Bs[ki][tc * 4];
      acc[0][0] += a.x * bv.x; acc[0][1] += a.x * bv.y; acc[0][2] += a.x * bv.z; acc[0][3] += a.x * bv.w;
      acc[1][0] += a.y * bv.x; acc[1][1] += a.y * bv.y; acc[1][2] += a.y * bv.z; acc[1][3] += a.y * bv.w;
      acc[2][0] += a.z * bv.x; acc[2][1] += a.z * bv.y; acc[2][2] += a.z * bv.z; acc[2][3] += a.z * bv.w;
      acc[3][0] += a.w * bv.x; acc[3][1] += a.w * bv.y; acc[3][2] += a.w * bv.z; acc[3][3] += a.w * bv.w;
    }
    __syncthreads();
  }
#pragma unroll
  for (int r = 0; r < 4; r++) {
    int mi = m0 + tr * 4 + r;
#pragma unroll
    for (int cc = 0; cc < 4; cc++) {
      int n = n0 + tc * 4 + cc;
      if (n < N) Cout[(size_t)mi * ldc + n] = acc[r][cc];
    }
  }
}

// ---------- reduce split-K gate partials + biases + LSTM pointwise ----------
__global__ __launch_bounds__(256) void k_lstm(const float* __restrict__ gpart,
                                              const float* __restrict__ b_ih,
                                              const float* __restrict__ b_hh,
                                              const int* __restrict__ llen,
                                              float* __restrict__ h, float* __restrict__ c,
                                              int t) {
  int idx = blockIdx.x * 256 + threadIdx.x;   // B*D = 65536
  int b = idx >> 9, d = idx & 511;
  if (t >= llen[b]) return;                   // inactive: h,c unchanged
  float g4[4];
#pragma unroll
  for (int g = 0; g < 4; g++) {
    int j = g * 512 + d;
    float s = b_ih[j] + b_hh[j];
#pragma unroll
    for (int z = 0; z < 4; z++) s += gpart[((size_t)z * 128 + b) * 2048 + j];
    g4[g] = s;
  }
  float i_ = sigmoidf_(g4[0]);
  float f_ = sigmoidf_(g4[1]);
  float gg = tanhf(g4[2]);
  float o_ = sigmoidf_(g4[3]);
  float cn = f_ * c[idx] + i_ * gg;
  float hn = o_ * tanhf(cn);
  c[idx] = cn;
  h[idx] = hn;
}

// ---------- reduce fc partials + bias + active mask + write ----------
__global__ __launch_bounds__(256) void k_fc_red(const float* __restrict__ fpart,
                                                const float* __restrict__ b_fc,
                                                const int* __restrict__ llen,
                                                float* __restrict__ dst, int t, int direct) {
  int idx = blockIdx.x * 256 + threadIdx.x;   // B*V = 512000
  int b = idx / 4000, v = idx - b * 4000;
  float s = 0.f;
  if (t < llen[b])
    s = fpart[(size_t)b * 4000 + v] + fpart[(size_t)(128 + b) * 4000 + v] + b_fc[v];
  if (direct) dst[((size_t)b * 4000 + v) * 32 + t] = s;
  else        dst[((size_t)t * 128 + b) * 4000 + v] = s;
}

// ---------- final transpose predsT[T,B,V] -> out[B,V,T] ----------
__global__ __launch_bounds__(256) void k_out_tr(const float* __restrict__ predsT,
                                                float* __restrict__ out) {
  __shared__ float tile[32][33];
  int b = blockIdx.y, v0 = blockIdx.x * 32;
  int tx = threadIdx.x & 31, ty = threadIdx.x >> 5;   // ty 0..7
  for (int i = 0; i < 32; i += 8) {
    int tt = ty + i;
    tile[tt][tx] = predsT[((size_t)tt * 128 + b) * 4000 + v0 + tx];
  }
  __syncthreads();
  for (int i = 0; i < 32; i += 8) {
    int v = v0 + ty + i;
    out[((size_t)b * 4000 + v) * 32 + tx] = tile[tx][ty + i];
  }
}

extern "C" void kernel_launch(void* const* d_in, const int* in_sizes, int n_in,
                              void* d_out, int out_size, void* d_ws, size_t ws_size,
                              hipStream_t stream) {
  (void)in_sizes; (void)n_in; (void)out_size;
  const float* avf   = (const float*)d_in[0];
  const float* rof   = (const float*)d_in[1];
  const float* objs  = (const float*)d_in[2];
  const float* rcl   = (const float*)d_in[3];
  const float* avx   = (const float*)d_in[4];
  const int*   lidx  = (const int*)d_in[5];
  const int*   llen  = (const int*)d_in[6];
  const float* embt  = (const float*)d_in[7];
  const float* iemb  = (const float*)d_in[8];
  const float* W_enc = (const float*)d_in[9];
  const float* b_enc = (const float*)d_in[10];
  const float* W_dec = (const float*)d_in[11];
  const float* b_dec = (const float*)d_in[12];
  const float* wfull = (const float*)d_in[13];
  const float* bfull = (const float*)d_in[14];
  const float* W_ih  = (const float*)d_in[15];
  const float* b_ih  = (const float*)d_in[16];
  const float* W_hh  = (const float*)d_in[17];
  const float* b_hh  = (const float*)d_in[18];
  const float* W_inh = (const float*)d_in[19];
  const float* b_inh = (const float*)d_in[20];
  const float* W_inc = (const float*)d_in[21];
  const float* b_inc = (const float*)d_in[22];
  const float* W_fb  = (const float*)d_in[23];
  const float* b_fb  = (const float*)d_in[24];
  const float* W_fc  = (const float*)d_in[25];
  const float* b_fc  = (const float*)d_in[26];

  float* ws = (float*)d_ws;
  size_t f = 0;
  auto A8 = [&](size_t n) { size_t o = f; f += (n + 63) & ~(size_t)63; return o; };
  float* att1  = ws + A8((size_t)128 * 128 * 512);
  float* Wcat  = ws + A8((size_t)2048 * XKP);
  float* wdT   = ws + A8(512 * 512);
  float* weT   = ws + A8(128 * 512);
  float* wihT  = ws + A8(384 * 512);
  float* wicT  = ws + A8(384 * 512);
  float* wfbT  = ws + A8(512 * 128);
  float* hbuf  = ws + A8(128 * 512);
  float* cbuf  = ws + A8(128 * 512);
  float* Xbuf  = ws + A8((size_t)128 * XKP);
  float* maskf = ws + A8(128 * 128);
  float* encm  = ws + A8(128 * 128);
  float* gpart = ws + A8((size_t)4 * 128 * 2048);
  float* fpart = ws + A8((size_t)2 * 128 * 4000);
  float* predsT = ws + A8((size_t)32 * 128 * 4000);
  bool useT = ws_size >= f * sizeof(float);

  float* out_pred  = (float*)d_out;
  float* out_alpha = out_pred + (size_t)16384000;
  float* out_mask  = out_alpha + (size_t)524288;

  // ---- setup ----
  k_transpose<<<dim3(16, 16), 256, 0, stream>>>(W_dec, wdT, 512, 512);
  k_transpose<<<dim3(4, 16),  256, 0, stream>>>(W_enc, weT, 512, 128);
  k_transpose<<<dim3(12, 16), 256, 0, stream>>>(W_inh, wihT, 512, 384);
  k_transpose<<<dim3(12, 16), 256, 0, stream>>>(W_inc, wicT, 512, 384);
  k_transpose<<<dim3(16, 4),  256, 0, stream>>>(W_fb, wfbT, 128, 512);
  k_wcat<<<2048, 256, 0, stream>>>(W_ih, W_hh, Wcat);
  k_mask<<<128, 128, 0, stream>>>(objs, rcl, avx, avf, maskf, encm, out_mask);
  k_init<<<128, 512, 0, stream>>>(encm, rof, wihT, wicT, b_inh, b_inc, hbuf, cbuf);
  k_att1<<<1024, 512, 0, stream>>>(avf, weT, b_enc, att1);

  // ---- decode loop ----
  for (int t = 0; t < 32; t++) {
    k_step_att<<<128, 512, 0, stream>>>(att1, hbuf, wdT, b_dec, wfull, bfull,
        avf, maskf, wfbT, b_fb, rof, embt, iemb, lidx, llen, Xbuf, out_alpha, t);
    k_gemm<<<dim3(32, 2, 4), 256, 0, stream>>>(Xbuf, XKP, Wcat, XKP, 2048, 304, gpart, 2048);
    k_lstm<<<256, 256, 0, stream>>>(gpart, b_ih, b_hh, llen, hbuf, cbuf, t);
    k_gemm<<<dim3(63, 2, 2), 256, 0, stream>>>(hbuf, 512, W_fc, 512, 4000, 256, fpart, 4000);
    k_fc_red<<<2000, 256, 0, stream>>>(fpart, b_fc, llen,
                                       useT ? predsT : out_pred, t, useT ? 0 : 1);
  }
  if (useT) k_out_tr<<<dim3(125, 128), 256, 0, stream>>>(predsT, out_pred);
}

// Round 4
// 2434.688 us; speedup vs baseline: 1.1213x; 1.1213x over previous
//
#include <hip/hip_runtime.h>
#include <hip/hip_bf16.h>
#include <math.h>

#define XKTOT 1196
#define XKP   1216

typedef unsigned short u16;
typedef short bf16x8 __attribute__((ext_vector_type(8)));
typedef float f32x4 __attribute__((ext_vector_type(4)));

static __device__ __forceinline__ float sigmoidf_(float x){ return 1.f/(1.f+expf(-x)); }
static __device__ __forceinline__ u16 f2bf(float x){ __hip_bfloat16 h = __float2bfloat16(x); return *reinterpret_cast<u16*>(&h); }
static __device__ __forceinline__ float bf2f(u16 u){ __hip_bfloat16 h; *reinterpret_cast<u16*>(&h) = u; return __bfloat162float(h); }

// ---------- generic 32x32 tiled transpose: in[R][C] -> out[C][R] ----------
__global__ __launch_bounds__(256) void k_transpose(const float* __restrict__ in,
                                                   float* __restrict__ out, int R, int C) {
  __shared__ float tile[32][33];
  int c0 = blockIdx.x * 32, r0 = blockIdx.y * 32;
  int tx = threadIdx.x & 31, ty = threadIdx.x >> 5;
  for (int i = 0; i < 32; i += 8) {
    int r = r0 + ty + i, c = c0 + tx;
    tile[ty + i][tx] = (r < R && c < C) ? in[(size_t)r * C + c] : 0.f;
  }
  __syncthreads();
  for (int i = 0; i < 32; i += 8) {
    int c = c0 + ty + i, r = r0 + tx;
    if (c < C && r < R) out[(size_t)c * R + r] = tile[tx][ty + i];
  }
}

// ---------- fp32 -> bf16 elementwise ----------
__global__ __launch_bounds__(256) void k_cvt(const float* __restrict__ in,
                                             u16* __restrict__ out, int n) {
  for (int i = blockIdx.x * 256 + threadIdx.x; i < n; i += gridDim.x * 256)
    out[i] = f2bf(in[i]);
}

// ---------- Wcat split hi/lo, gate-interleaved: row n'=d*4+g <- j=g*512+d ----------
__global__ __launch_bounds__(256) void k_wcat_split(const float* __restrict__ W_ih,
                                                    const float* __restrict__ W_hh,
                                                    u16* __restrict__ Whi,
                                                    u16* __restrict__ Wlo) {
  int np = blockIdx.x;               // 0..2047
  int d = np >> 2, g = np & 3;
  int j = g * 512 + d;               // torch gate row
  for (int c = threadIdx.x; c < XKP; c += 256) {
    float v;
    if (c < 684)        v = W_ih[(size_t)j * 684 + c];
    else if (c < 1196)  v = W_hh[(size_t)j * 512 + (c - 684)];
    else                v = 0.f;
    u16 hi = f2bf(v);
    u16 lo = f2bf(v - bf2f(hi));
    Whi[(size_t)np * XKP + c] = hi;
    Wlo[(size_t)np * XKP + c] = lo;
  }
}

// ---------- objectness mask + top-16 order stat + enc mean ----------
__global__ __launch_bounds__(128) void k_mask(const float* __restrict__ objs,
                                              const float* __restrict__ rcl,
                                              const float* __restrict__ avx,
                                              const float* __restrict__ enc,
                                              float* __restrict__ maskf,
                                              float* __restrict__ encmean,
                                              float* __restrict__ out_mask) {
  int b = blockIdx.x, k = threadIdx.x;
  __shared__ float dsh[128];
  __shared__ float maxd;
  float s0 = objs[(size_t)(b * 128 + k) * 2 + 0];
  float s1 = objs[(size_t)(b * 128 + k) * 2 + 1];
  float mx = fmaxf(s0, s1);
  float e0 = expf(s0 - mx), e1 = expf(s1 - mx);
  float p  = e1 / (e0 + e1);
  bool om  = p > 0.75f;
  float dx = rcl[b * 3 + 0] - avx[(size_t)(b * 128 + k) * 3 + 0];
  float dy = rcl[b * 3 + 1] - avx[(size_t)(b * 128 + k) * 3 + 1];
  float dz = rcl[b * 3 + 2] - avx[(size_t)(b * 128 + k) * 3 + 2];
  float dist = sqrtf(dx * dx + dy * dy + dz * dz);
  float dm = om ? dist : INFINITY;
  dsh[k] = dm;
  __syncthreads();
  float v = dm; int clt = 0, cle = 0;
  for (int j = 0; j < 128; j++) { float o = dsh[j]; clt += (o < v); cle += (o <= v); }
  if (clt < 16 && cle >= 16) maxd = v;
  __syncthreads();
  bool msk = om && (dm <= maxd);
  maskf[b * 128 + k]    = msk ? 1.f : 0.f;
  out_mask[b * 128 + k] = msk ? 1.f : 0.f;
  float s = 0.f;
  for (int kk = 0; kk < 128; kk++) s += enc[(size_t)(b * 128 + kk) * 128 + k];
  encmean[b * 128 + k] = s * (1.f / 128.f);
}

// ---------- h0/c0 init ----------
__global__ __launch_bounds__(512) void k_init(const float* __restrict__ encm,
                                              const float* __restrict__ rof,
                                              const float* __restrict__ wihT,
                                              const float* __restrict__ wicT,
                                              const float* __restrict__ bh,
                                              const float* __restrict__ bc,
                                              float* __restrict__ h, float* __restrict__ c,
                                              u16* __restrict__ hb16) {
  int b = blockIdx.x, d = threadIdx.x;
  __shared__ float xin[384];
  if (d < 128) xin[d] = encm[b * 128 + d];
  else if (d < 384) xin[d] = rof[(size_t)b * 256 + (d - 128)];
  __syncthreads();
  float ah = bh[d], ac = bc[d];
  for (int i = 0; i < 384; i++) {
    float x = xin[i];
    ah += x * wihT[(size_t)i * 512 + d];
    ac += x * wicT[(size_t)i * 512 + d];
  }
  size_t idx = (size_t)b * 512 + d;
  h[idx] = ah;
  c[idx] = ac;
  hb16[idx] = f2bf(ah);
}

// ---------- att1 via MFMA: [16384,512] = enc16[16384,128] x We16[512,128]^T ----------
__global__ __launch_bounds__(256) void k_att1m(const u16* __restrict__ enc16,
                                               const u16* __restrict__ We16,
                                               const float* __restrict__ b_enc,
                                               float* __restrict__ att1) {
  int w = threadIdx.x >> 6, lane = threadIdx.x & 63;
  int gw = blockIdx.x * 4 + w;          // 0..8191
  int nt = gw & 15, mt = gw >> 4;       // mt 0..511 (32-row), nt 0..15 (32-col)
  int m0 = mt * 32, n0 = nt * 32;
  int rc = lane & 15, kb = lane >> 4;
  const bf16x8* a0 = (const bf16x8*)(enc16 + (size_t)(m0 + rc) * 128) + kb;
  const bf16x8* a1 = (const bf16x8*)(enc16 + (size_t)(m0 + 16 + rc) * 128) + kb;
  const bf16x8* b0 = (const bf16x8*)(We16 + (size_t)(n0 + rc) * 128) + kb;
  const bf16x8* b1 = (const bf16x8*)(We16 + (size_t)(n0 + 16 + rc) * 128) + kb;
  f32x4 z = {0.f, 0.f, 0.f, 0.f};
  f32x4 acc00 = z, acc01 = z, acc10 = z, acc11 = z;
#pragma unroll
  for (int kk = 0; kk < 4; kk++) {
    bf16x8 av0 = a0[kk * 4], av1 = a1[kk * 4];
    bf16x8 bv0 = b0[kk * 4], bv1 = b1[kk * 4];
    acc00 = __builtin_amdgcn_mfma_f32_16x16x32_bf16(av0, bv0, acc00, 0, 0, 0);
    acc01 = __builtin_amdgcn_mfma_f32_16x16x32_bf16(av0, bv1, acc01, 0, 0, 0);
    acc10 = __builtin_amdgcn_mfma_f32_16x16x32_bf16(av1, bv0, acc10, 0, 0, 0);
    acc11 = __builtin_amdgcn_mfma_f32_16x16x32_bf16(av1, bv1, acc11, 0, 0, 0);
  }
  int col = lane & 15, rbase = (lane >> 4) * 4;
#pragma unroll
  for (int r = 0; r < 4; r++) {
    int r0g = m0 + rbase + r;
    att1[(size_t)r0g * 512 + n0 + col]        = acc00[r] + b_enc[n0 + col];
    att1[(size_t)r0g * 512 + n0 + 16 + col]   = acc01[r] + b_enc[n0 + 16 + col];
    att1[(size_t)(r0g + 16) * 512 + n0 + col]      = acc10[r] + b_enc[n0 + col];
    att1[(size_t)(r0g + 16) * 512 + n0 + 16 + col] = acc11[r] + b_enc[n0 + 16 + col];
  }
}

// ---------- per-step fused attention + softmax + awe + gate + X build (bf16 split out) ----------
__global__ __launch_bounds__(512) void k_step_att(
    const float* __restrict__ att1, const float* __restrict__ h,
    const float* __restrict__ wdT, const float* __restrict__ b_dec,
    const float* __restrict__ wfull, const float* __restrict__ bfull,
    const float* __restrict__ enc, const float* __restrict__ maskf,
    const float* __restrict__ wfbT, const float* __restrict__ b_fbeta,
    const float* __restrict__ rof, const float* __restrict__ embt,
    const float* __restrict__ iemb, const int* __restrict__ lidx,
    const int* __restrict__ llen, u16* __restrict__ Xhi, u16* __restrict__ Xlo,
    float* __restrict__ alphas_out, int t) {
  int b = blockIdx.x, tid = threadIdx.x;
  __shared__ float hs[512], att2[512], wf[512], attk[128], alph[128], awes[128];
  __shared__ float red1[2], red2[2];
  hs[tid] = h[(size_t)b * 512 + tid];
  wf[tid] = wfull[tid];
  __syncthreads();
  {
    float acc = b_dec[tid];
    for (int i = 0; i < 512; i++) acc += hs[i] * wdT[(size_t)i * 512 + tid];
    att2[tid] = acc;
  }
  __syncthreads();
  int k = tid >> 2, j = tid & 3;
  {
    const float4* a1 = (const float4*)(att1 + (size_t)(b * 128 + k) * 512 + j * 128);
    float s = 0.f;
#pragma unroll 4
    for (int i = 0; i < 32; i++) {
      float4 v = a1[i];
      int base = j * 128 + i * 4;
      s += fmaxf(v.x + att2[base + 0], 0.f) * wf[base + 0];
      s += fmaxf(v.y + att2[base + 1], 0.f) * wf[base + 1];
      s += fmaxf(v.z + att2[base + 2], 0.f) * wf[base + 2];
      s += fmaxf(v.w + att2[base + 3], 0.f) * wf[base + 3];
    }
    s += __shfl_xor(s, 1);
    s += __shfl_xor(s, 2);
    if (j == 0) attk[k] = s + bfull[0];
  }
  __syncthreads();
  float mk = 0.f, av = 0.f;
  if (tid < 128) { mk = maskf[b * 128 + tid]; av = attk[tid]; }
  float nv = (tid < 128 && mk != 0.f) ? av : -INFINITY;
  float wm = nv;
#pragma unroll
  for (int o = 32; o > 0; o >>= 1) wm = fmaxf(wm, __shfl_xor(wm, o));
  if (tid < 128 && (tid & 63) == 0) red1[tid >> 6] = wm;
  __syncthreads();
  float m = fmaxf(red1[0], red1[1]);
  float e = 0.f;
  if (tid < 128 && mk != 0.f) e = expf(av - m);
  float sred = e;
#pragma unroll
  for (int o = 32; o > 0; o >>= 1) sred += __shfl_xor(sred, o);
  if (tid < 128 && (tid & 63) == 0) red2[tid >> 6] = sred;
  __syncthreads();
  float dsum = red2[0] + red2[1];
  float alpha = (dsum > 0.f) ? e / fmaxf(dsum, 1e-30f) : 0.f;
  int active = t < llen[b];
  if (tid < 128) {
    alph[tid] = alpha;
    alphas_out[(size_t)(b * 32 + t) * 128 + tid] = active ? alpha : 0.f;
  }
  __syncthreads();
  float awe_v = 0.f;
  if (tid < 128) {
    for (int kk = 0; kk < 128; kk++)
      awe_v += alph[kk] * enc[(size_t)(b * 128 + kk) * 128 + tid];
  }
  {
    int v = tid >> 2;
    float g = 0.f;
    for (int ii = 0; ii < 128; ii++) {
      int i = j * 128 + ii;
      g += hs[i] * wfbT[(size_t)i * 128 + v];
    }
    g += __shfl_xor(g, 1);
    g += __shfl_xor(g, 2);
    if (j == 0) attk[v] = sigmoidf_(g + b_fbeta[v]);
  }
  __syncthreads();
  if (tid < 128) awes[tid] = awe_v * attk[tid];
  __syncthreads();
  // X row b: [emb(300) | awe(128) | rof(256) | h(512) | pad(20)] -> bf16 hi/lo
  const float* esrc = (t == 0) ? iemb : (embt + (size_t)lidx[b * 32 + (t - 1)] * 300);
  for (int c = tid; c < XKP; c += 512) {
    float val;
    if (c < 300)       val = esrc[c];
    else if (c < 428)  val = awes[c - 300];
    else if (c < 684)  val = rof[(size_t)b * 256 + (c - 428)];
    else if (c < 1196) val = hs[c - 684];
    else               val = 0.f;
    u16 hi = f2bf(val);
    Xhi[(size_t)b * XKP + c] = hi;
    Xlo[(size_t)b * XKP + c] = f2bf(val - bf2f(hi));
  }
}

// ---------- gates GEMM (bf16 split, MFMA) + fused LSTM pointwise ----------
// C[128,2048'] = X[128,1216] x Wcat'[2048,1216]^T ; n' = d*4+g interleaved
__global__ __launch_bounds__(256) void k_gates(const u16* __restrict__ Xhi,
                                               const u16* __restrict__ Xlo,
                                               const u16* __restrict__ Whi,
                                               const u16* __restrict__ Wlo,
                                               const float* __restrict__ b_ih,
                                               const float* __restrict__ b_hh,
                                               const int* __restrict__ llen,
                                               float* __restrict__ h, float* __restrict__ c,
                                               u16* __restrict__ hb16, int t) {
  int w = threadIdx.x >> 6, lane = threadIdx.x & 63;
  int mt = blockIdx.x >> 5;                 // 0..7 : block-shared M-tile (A reuse in L1)
  int nt = (blockIdx.x & 31) * 4 + w;       // 0..127
  int m0 = mt * 16, n0 = nt * 16;
  int rc = lane & 15, kb = lane >> 4;
  const bf16x8* aHi = (const bf16x8*)(Xhi + (size_t)(m0 + rc) * XKP) + kb;
  const bf16x8* aLo = (const bf16x8*)(Xlo + (size_t)(m0 + rc) * XKP) + kb;
  const bf16x8* bHi = (const bf16x8*)(Whi + (size_t)(n0 + rc) * XKP) + kb;
  const bf16x8* bLo = (const bf16x8*)(Wlo + (size_t)(n0 + rc) * XKP) + kb;
  f32x4 acc = {0.f, 0.f, 0.f, 0.f};
#pragma unroll 2
  for (int kk = 0; kk < 38; kk++) {
    bf16x8 ah = aHi[kk * 4], al = aLo[kk * 4];
    bf16x8 bh = bHi[kk * 4], bl = bLo[kk * 4];
    acc = __builtin_amdgcn_mfma_f32_16x16x32_bf16(ah, bh, acc, 0, 0, 0);
    acc = __builtin_amdgcn_mfma_f32_16x16x32_bf16(al, bh, acc, 0, 0, 0);
    acc = __builtin_amdgcn_mfma_f32_16x16x32_bf16(ah, bl, acc, 0, 0, 0);
  }
  __shared__ float tile[4][16][17];
#pragma unroll
  for (int r = 0; r < 4; r++) tile[w][(lane >> 4) * 4 + r][lane & 15] = acc[r];
  __syncthreads();
  // LSTM pointwise: lane -> (b = m0 + (lane&15), d = nt*4 + (lane>>4))
  int lb = lane & 15, ld = lane >> 4;
  int b = m0 + lb, d = nt * 4 + ld;
  if (t < llen[b]) {
    float g4[4];
#pragma unroll
    for (int g = 0; g < 4; g++) {
      int jj = g * 512 + d;
      g4[g] = tile[w][lb][ld * 4 + g] + b_ih[jj] + b_hh[jj];
    }
    float i_ = sigmoidf_(g4[0]);
    float f_ = sigmoidf_(g4[1]);
    float gg = tanhf(g4[2]);
    float o_ = sigmoidf_(g4[3]);
    size_t idx = (size_t)b * 512 + d;
    float cn = f_ * c[idx] + i_ * gg;
    float hn = o_ * tanhf(cn);
    c[idx] = cn;
    h[idx] = hn;
    hb16[idx] = f2bf(hn);
  }
}

// ---------- fc GEMM (bf16 MFMA) + bias + active mask + store ----------
__global__ __launch_bounds__(256) void k_fc(const u16* __restrict__ hb16,
                                            const u16* __restrict__ Wfc16,
                                            const float* __restrict__ b_fc,
                                            const int* __restrict__ llen,
                                            float* __restrict__ dst, int t, int direct) {
  int w = threadIdx.x >> 6, lane = threadIdx.x & 63;
  int gw = blockIdx.x * 4 + w;          // 0..1999
  int mt = gw & 7, nt = gw >> 3;        // nt 0..249
  int m0 = mt * 16, n0 = nt * 16;
  int rc = lane & 15, kb = lane >> 4;
  const bf16x8* aP = (const bf16x8*)(hb16 + (size_t)(m0 + rc) * 512) + kb;
  const bf16x8* bP = (const bf16x8*)(Wfc16 + (size_t)(n0 + rc) * 512) + kb;
  f32x4 acc = {0.f, 0.f, 0.f, 0.f};
#pragma unroll 4
  for (int kk = 0; kk < 16; kk++)
    acc = __builtin_amdgcn_mfma_f32_16x16x32_bf16(aP[kk * 4], bP[kk * 4], acc, 0, 0, 0);
  int col = lane & 15, rbase = (lane >> 4) * 4;
  int v = n0 + col;
  float bias = b_fc[v];
#pragma unroll
  for (int r = 0; r < 4; r++) {
    int b = m0 + rbase + r;
    float val = (t < llen[b]) ? (acc[r] + bias) : 0.f;
    if (direct) dst[((size_t)b * 4000 + v) * 32 + t] = val;
    else        dst[((size_t)(t * 128 + b)) * 4000 + v] = val;
  }
}

// ---------- final transpose predsT[T,B,V] -> out[B,V,T] ----------
__global__ __launch_bounds__(256) void k_out_tr(const float* __restrict__ predsT,
                                                float* __restrict__ out) {
  __shared__ float tile[32][33];
  int b = blockIdx.y, v0 = blockIdx.x * 32;
  int tx = threadIdx.x & 31, ty = threadIdx.x >> 5;
  for (int i = 0; i < 32; i += 8) {
    int tt = ty + i;
    tile[tt][tx] = predsT[((size_t)tt * 128 + b) * 4000 + v0 + tx];
  }
  __syncthreads();
  for (int i = 0; i < 32; i += 8) {
    int v = v0 + ty + i;
    out[((size_t)b * 4000 + v) * 32 + tx] = tile[tx][ty + i];
  }
}

extern "C" void kernel_launch(void* const* d_in, const int* in_sizes, int n_in,
                              void* d_out, int out_size, void* d_ws, size_t ws_size,
                              hipStream_t stream) {
  (void)in_sizes; (void)n_in; (void)out_size;
  const float* avf   = (const float*)d_in[0];
  const float* rof   = (const float*)d_in[1];
  const float* objs  = (const float*)d_in[2];
  const float* rcl   = (const float*)d_in[3];
  const float* avx   = (const float*)d_in[4];
  const int*   lidx  = (const int*)d_in[5];
  const int*   llen  = (const int*)d_in[6];
  const float* embt  = (const float*)d_in[7];
  const float* iemb  = (const float*)d_in[8];
  const float* W_enc = (const float*)d_in[9];
  const float* b_enc = (const float*)d_in[10];
  const float* W_dec = (const float*)d_in[11];
  const float* b_dec = (const float*)d_in[12];
  const float* wfull = (const float*)d_in[13];
  const float* bfull = (const float*)d_in[14];
  const float* W_ih  = (const float*)d_in[15];
  const float* b_ih  = (const float*)d_in[16];
  const float* W_hh  = (const float*)d_in[17];
  const float* b_hh  = (const float*)d_in[18];
  const float* W_inh = (const float*)d_in[19];
  const float* b_inh = (const float*)d_in[20];
  const float* W_inc = (const float*)d_in[21];
  const float* b_inc = (const float*)d_in[22];
  const float* W_fb  = (const float*)d_in[23];
  const float* b_fb  = (const float*)d_in[24];
  const float* W_fc  = (const float*)d_in[25];
  const float* b_fc  = (const float*)d_in[26];

  float* ws = (float*)d_ws;
  size_t f = 0;
  auto A8 = [&](size_t n) { size_t o = f; f += (n + 63) & ~(size_t)63; return o; };
  float* att1  = ws + A8((size_t)128 * 128 * 512);
  float* wdT   = ws + A8(512 * 512);
  float* wihT  = ws + A8(384 * 512);
  float* wicT  = ws + A8(384 * 512);
  float* wfbT  = ws + A8(512 * 128);
  float* hbuf  = ws + A8(128 * 512);
  float* cbuf  = ws + A8(128 * 512);
  float* maskf = ws + A8(128 * 128);
  float* encm  = ws + A8(128 * 128);
  u16*   Xhi   = (u16*)(ws + A8((size_t)128 * XKP / 2));
  u16*   Xlo   = (u16*)(ws + A8((size_t)128 * XKP / 2));
  u16*   WcatHi= (u16*)(ws + A8((size_t)2048 * XKP / 2));
  u16*   WcatLo= (u16*)(ws + A8((size_t)2048 * XKP / 2));
  u16*   enc16 = (u16*)(ws + A8((size_t)128 * 128 * 128 / 2));
  u16*   We16  = (u16*)(ws + A8((size_t)512 * 128 / 2));
  u16*   Wfc16 = (u16*)(ws + A8((size_t)4000 * 512 / 2));
  u16*   hb16  = (u16*)(ws + A8((size_t)128 * 512 / 2));
  float* predsT= ws + A8((size_t)32 * 128 * 4000);
  bool useT = ws_size >= f * sizeof(float);

  float* out_pred  = (float*)d_out;
  float* out_alpha = out_pred + (size_t)16384000;
  float* out_mask  = out_alpha + (size_t)524288;

  // ---- setup ----
  k_transpose<<<dim3(16, 16), 256, 0, stream>>>(W_dec, wdT, 512, 512);
  k_transpose<<<dim3(12, 16), 256, 0, stream>>>(W_inh, wihT, 512, 384);
  k_transpose<<<dim3(12, 16), 256, 0, stream>>>(W_inc, wicT, 512, 384);
  k_transpose<<<dim3(16, 4),  256, 0, stream>>>(W_fb, wfbT, 128, 512);
  k_wcat_split<<<2048, 256, 0, stream>>>(W_ih, W_hh, WcatHi, WcatLo);
  k_cvt<<<2048, 256, 0, stream>>>(avf, enc16, 128 * 128 * 128);
  k_cvt<<<256,  256, 0, stream>>>(W_enc, We16, 512 * 128);
  k_cvt<<<2048, 256, 0, stream>>>(W_fc, Wfc16, 4000 * 512);
  k_mask<<<128, 128, 0, stream>>>(objs, rcl, avx, avf, maskf, encm, out_mask);
  k_init<<<128, 512, 0, stream>>>(encm, rof, wihT, wicT, b_inh, b_inc, hbuf, cbuf, hb16);
  k_att1m<<<2048, 256, 0, stream>>>(enc16, We16, b_enc, att1);

  // ---- decode loop: 3 kernels/step ----
  for (int t = 0; t < 32; t++) {
    k_step_att<<<128, 512, 0, stream>>>(att1, hbuf, wdT, b_dec, wfull, bfull,
        avf, maskf, wfbT, b_fb, rof, embt, iemb, lidx, llen, Xhi, Xlo, out_alpha, t);
    k_gates<<<256, 256, 0, stream>>>(Xhi, Xlo, WcatHi, WcatLo, b_ih, b_hh, llen,
                                     hbuf, cbuf, hb16, t);
    k_fc<<<500, 256, 0, stream>>>(hb16, Wfc16, b_fc, llen,
                                  useT ? predsT : out_pred, t, useT ? 0 : 1);
  }
  if (useT) k_out_tr<<<dim3(125, 128), 256, 0, stream>>>(predsT, out_pred);
}